// Round 2
// baseline (684.283 us; speedup 1.0000x reference)
//
#include <hip/hip_runtime.h>
#include <math.h>

#define NB 8
#define NS 256
#define NH 768
#define NE 20000
#define NT 100000

// ---------------- wave helpers ----------------
__device__ __forceinline__ float wsum(float v) {
#pragma unroll
  for (int off = 32; off; off >>= 1) v += __shfl_xor(v, off, 64);
  return v;
}
__device__ __forceinline__ float wmax(float v) {
#pragma unroll
  for (int off = 32; off; off >>= 1) v = fmaxf(v, __shfl_xor(v, off, 64));
  return v;
}

// ---------------- K0: wv = W_v @ W_p  (768) ----------------
__global__ void k_prep(const float* __restrict__ Wv, const float* __restrict__ Wp,
                       float* __restrict__ wv) {
  int wave = threadIdx.x >> 6, lane = threadIdx.x & 63;
  int h = blockIdx.x * 4 + wave;           // 192 blocks * 4 waves = 768
  const float4* Wv4 = (const float4*)Wv;   // (768, 256) -> 64 f4 per row
  const float4* Wp4 = (const float4*)Wp;
  float4 a = Wv4[h * 64 + lane];
  float4 p = Wp4[lane];
  float v = a.x * p.x + a.y * p.y + a.z * p.z + a.w * p.w;
  v = wsum(v);
  if (lane == 0) wv[h] = v;
}

// ---------------- K1: score[b,s] = lhs[b,s,:] . wv ----------------
__global__ void k_score(const float* __restrict__ lhs, const float* __restrict__ wv,
                        float* __restrict__ score) {
  int chunk = blockIdx.x, b = blockIdx.y;
  int wave = threadIdx.x >> 6, lane = threadIdx.x & 63;
  const float4* lhs4 = (const float4*)lhs;  // row = 192 f4
  const float4* wv4 = (const float4*)wv;
  float4 w0 = wv4[lane], w1 = wv4[lane + 64], w2 = wv4[lane + 128];
#pragma unroll
  for (int i = 0; i < 8; i++) {
    int s = chunk * 32 + i * 4 + wave;
    const float4* row = lhs4 + (size_t)(b * NS + s) * 192;
    float4 a0 = row[lane], a1 = row[lane + 64], a2 = row[lane + 128];
    float v = a0.x * w0.x + a0.y * w0.y + a0.z * w0.z + a0.w * w0.w
            + a1.x * w1.x + a1.y * w1.y + a1.z * w1.z + a1.w * w1.w
            + a2.x * w2.x + a2.y * w2.y + a2.z * w2.z + a2.w * w2.w;
    v = wsum(v);
    if (lane == 0) score[b * NS + s] = v;
  }
}

// ---------------- K2: softmax(score) -> D[b, h-chunk] ----------------
__global__ void k_D(const float* __restrict__ lhs, const float* __restrict__ mask,
                    const float* __restrict__ score, float* __restrict__ Dv) {
  int b = blockIdx.x, chunk = blockIdx.y;
  int tid = threadIdx.x;  // 256
  __shared__ float red[256];
  __shared__ float pm[NS];
  float sv = score[b * NS + tid];
  red[tid] = sv; __syncthreads();
  for (int st = 128; st; st >>= 1) {
    if (tid < st) red[tid] = fmaxf(red[tid], red[tid + st]);
    __syncthreads();
  }
  float M = red[0]; __syncthreads();
  float e = expf(sv - M);
  red[tid] = e; __syncthreads();
  for (int st = 128; st; st >>= 1) {
    if (tid < st) red[tid] += red[tid + st];
    __syncthreads();
  }
  float Ssum = red[0];
  pm[tid] = (e / Ssum) * mask[b * NS + tid];
  __syncthreads();
  int h = chunk * 256 + tid;
  float acc = 0.f;
#pragma unroll 4
  for (int s = 0; s < NS; s++) acc += pm[s] * lhs[(size_t)(b * NS + s) * NH + h];
  Dv[b * NH + h] = acc;
}

// ---------------- K3: raw dots D@[W_r | W_c | L_w] for all 8 batches ----------------
__global__ void k_small(const float* __restrict__ Dv, const float* __restrict__ Wr,
                        const float* __restrict__ Wc, const float* __restrict__ Lw,
                        float* __restrict__ rels_raw, float* __restrict__ checks_raw,
                        float* __restrict__ LD) {
  __shared__ float Dl[NB * NH];        // 24 KB
  __shared__ float part[4][64][8];     // 8 KB
  int tid = threadIdx.x;
  for (int i = tid; i < NB * NH; i += 256) Dl[i] = Dv[i];
  __syncthreads();
  int c = tid & 63, q = tid >> 6;
  int C = blockIdx.x * 64 + c;         // 0..1373 valid
  const float* Wb = nullptr;
  float* outp = nullptr;
  int stride = 0, ostride = 0, col = 0;
  bool valid = (C < 1374);
  if (C < 600)      { Wb = Wr; stride = 600; col = C;       outp = rels_raw;   ostride = 600; }
  else if (C < 606) { Wb = Wc; stride = 6;   col = C - 600; outp = checks_raw; ostride = 6; }
  else if (valid)   { Wb = Lw; stride = 768; col = C - 606; outp = LD;         ostride = 768; }
  float p[8] = {0, 0, 0, 0, 0, 0, 0, 0};
  if (valid) {
    int h0 = q * 192;
    for (int h = h0; h < h0 + 192; h++) {
      float w = Wb[(size_t)h * stride + col];
#pragma unroll
      for (int b = 0; b < 8; b++) p[b] += Dl[b * NH + h] * w;
    }
  }
#pragma unroll
  for (int b = 0; b < 8; b++) part[q][c][b] = p[b];
  __syncthreads();
  if (q == 0 && valid) {
    for (int b = 0; b < 8; b++) {
      float v = part[0][c][b] + part[1][c][b] + part[2][c][b] + part[3][c][b];
      outp[b * ostride + col] = v;
    }
  }
}

// ---------------- K4: softmax rels_seq rows (200) + checks_seq rows (2), in place ----------------
__global__ void k_small2(float* __restrict__ rels, float* __restrict__ checks) {
  int b = blockIdx.x;
  int hop = threadIdx.x >> 6, lane = threadIdx.x & 63;  // 192 threads = 3 waves
  float* r = rels + (size_t)(b * 3 + hop) * 200;
  float v0 = r[lane], v1 = r[lane + 64], v2 = r[lane + 128];
  float v3 = (lane < 8) ? r[lane + 192] : -INFINITY;
  float m = wmax(fmaxf(fmaxf(v0, v1), fmaxf(v2, v3)));
  float e0 = expf(v0 - m), e1 = expf(v1 - m), e2 = expf(v2 - m);
  float e3 = (lane < 8) ? expf(v3 - m) : 0.f;
  float s = wsum(e0 + e1 + e2 + e3);
  r[lane] = e0 / s; r[lane + 64] = e1 / s; r[lane + 128] = e2 / s;
  if (lane < 8) r[lane + 192] = e3 / s;
  if (lane == 0) {
    float* cc = checks + b * 6 + hop * 2;
    float c0 = cc[0], c1 = cc[1];
    float mm = fmaxf(c0, c1);
    float f0 = expf(c0 - mm), f1 = expf(c1 - mm);
    cc[0] = f0 / (f0 + f1); cc[1] = f1 / (f0 + f1);
  }
}

// ---------------- K5: scores[b,e] = sum_{t,h} LD[b,h] * EE[e,t,h]  (246 MB pass) ----------------
__global__ __launch_bounds__(256) void k_scores(const float* __restrict__ EE,
                                                const float* __restrict__ LD,
                                                float* __restrict__ scores) {
  int wave = threadIdx.x >> 6, lane = threadIdx.x & 63;
  int e = blockIdx.x * 4 + wave;          // 5000*4 = 20000 exact
  const float4* EE4 = (const float4*)EE;  // 768 f4 per entity
  const float4* LD4 = (const float4*)LD;  // 192 f4 per batch
  float4 ld[3][8];
#pragma unroll
  for (int ph = 0; ph < 3; ph++)
#pragma unroll
    for (int b = 0; b < 8; b++) ld[ph][b] = LD4[b * 192 + ph * 64 + lane];
  float acc[8] = {0, 0, 0, 0, 0, 0, 0, 0};
  const float4* base = EE4 + (size_t)e * 768 + lane;
#pragma unroll
  for (int k = 0; k < 12; k++) {
    float4 v = base[k * 64];
    const int ph = k % 3;  // compile-time with unroll
#pragma unroll
    for (int b = 0; b < 8; b++)
      acc[b] += v.x * ld[ph][b].x + v.y * ld[ph][b].y + v.z * ld[ph][b].z + v.w * ld[ph][b].w;
  }
#pragma unroll
  for (int off = 32; off; off >>= 1)
#pragma unroll
    for (int b = 0; b < 8; b++) acc[b] += __shfl_xor(acc[b], off, 64);
  if (lane == 0) {
#pragma unroll
    for (int b = 0; b < 8; b++) scores[b * NE + e] = acc[b];
  }
}

// ---------------- K6: one hop scatter: acc[b, tails] += r_seq[rels] * e[heads] ----------------
__global__ void k_scatter(const int* __restrict__ heads, const int* __restrict__ rels,
                          const int* __restrict__ tails, const float* __restrict__ rels_seq,
                          const float* __restrict__ init_ent, const float* __restrict__ walk,
                          float* __restrict__ acc, int hop) {
  int t = blockIdx.x * 256 + threadIdx.x;
  if (t >= NB * NT) return;
  int b = t / NT;
  int hi = heads[t], ri = rels[t], ti = tails[t];
  float ev = (hop == 0) ? init_ent[(size_t)b * NE + hi]
                        : walk[((size_t)(b * 3) + hop - 1) * NE + hi];
  float rv = rels_seq[(size_t)(b * 3 + hop) * 200 + ri];
  atomicAdd(&acc[(size_t)b * NE + ti], rv * ev);
}

// ---------------- K7: normalize hop output, write walk, re-zero acc ----------------
__global__ void k_norm(float* __restrict__ acc, float* __restrict__ walk, int hop) {
  int b = blockIdx.x, tid = threadIdx.x;  // 1024
  float s = 0.f;
  for (int e = tid; e < NE; e += 1024) s += acc[(size_t)b * NE + e];
  s = wsum(s);
  __shared__ float red[16];
  __shared__ float stot;
  if ((tid & 63) == 0) red[tid >> 6] = s;
  __syncthreads();
  if (tid == 0) {
    float tt = 0.f;
    for (int i = 0; i < 16; i++) tt += red[i];
    stot = tt + 1e-6f;
  }
  __syncthreads();
  float denom = stot;
  float* w = walk + (size_t)(b * 3 + hop) * NE;
  for (int e = tid; e < NE; e += 1024) {
    w[e] = acc[(size_t)b * NE + e] / denom;
    acc[(size_t)b * NE + e] = 0.f;  // ready for next hop
  }
}

// ---------------- K8: checks softmax + combine -> ents ----------------
__global__ void k_final(const float* __restrict__ walk, const float* __restrict__ scores,
                        const float* __restrict__ checks_seq, float* __restrict__ out) {
  int row = blockIdx.x;  // b*3 + hop, 24 rows
  int b = row / 3, hop = row % 3;
  const float* w = walk + (size_t)row * NE;
  const float* sc = scores + (size_t)b * NE;
  int tid = threadIdx.x;  // 256
  __shared__ float red[4];
  __shared__ float MM, SS;
  float m = -INFINITY;
  for (int e = tid; e < NE; e += 256) m = fmaxf(m, w[e] * sc[e]);
  m = wmax(m);
  if ((tid & 63) == 0) red[tid >> 6] = m;
  __syncthreads();
  if (tid == 0) MM = fmaxf(fmaxf(red[0], red[1]), fmaxf(red[2], red[3]));
  __syncthreads();
  float M = MM;
  float s = 0.f;
  for (int e = tid; e < NE; e += 256) s += expf(w[e] * sc[e] - M);
  s = wsum(s);
  if ((tid & 63) == 0) red[tid >> 6] = s;
  __syncthreads();
  if (tid == 0) SS = red[0] + red[1] + red[2] + red[3];
  __syncthreads();
  float Sv = SS;
  float cs0 = checks_seq[b * 6 + hop * 2 + 0];
  float cs1 = checks_seq[b * 6 + hop * 2 + 1];
  for (int e = tid; e < NE; e += 256) {
    float we = w[e];
    out[(size_t)row * NE + e] = cs0 * we + cs1 * (expf(we * sc[e] - M) / Sv);
  }
}

// ---------------- launch ----------------
extern "C" void kernel_launch(void* const* d_in, const int* in_sizes, int n_in,
                              void* d_out, int out_size, void* d_ws, size_t ws_size,
                              hipStream_t stream) {
  const float* lhs      = (const float*)d_in[0];
  const float* mask     = (const float*)d_in[1];
  const float* init_ent = (const float*)d_in[2];
  const float* EE       = (const float*)d_in[3];
  // d_in[4] = W_q: unused — its contribution is constant over s and cancels in softmax(axis=1)
  const float* Wv       = (const float*)d_in[5];
  const float* Wp       = (const float*)d_in[6];
  const float* Wr       = (const float*)d_in[7];
  const float* Wc       = (const float*)d_in[8];
  const float* Lw       = (const float*)d_in[9];
  const int* heads      = (const int*)d_in[10];
  const int* rels       = (const int*)d_in[11];
  const int* tails      = (const int*)d_in[12];
  float* out = (float*)d_out;
  float* ws = (float*)d_ws;

  // ws layout (floats); total 819,952 floats ~= 3.28 MB
  float* wv         = ws + 0;       // 768
  float* score      = ws + 768;     // 2048
  float* Dv         = ws + 2816;    // 6144
  float* LD         = ws + 8960;    // 6144
  float* rels_seq   = ws + 15104;   // 4800
  float* checks_seq = ws + 19904;   // 48
  float* scores     = ws + 19952;   // 160000
  float* acc        = ws + 179952;  // 160000
  float* walk       = ws + 339952;  // 480000

  hipMemsetAsync(acc, 0, (size_t)NB * NE * sizeof(float), stream);
  k_prep<<<192, 256, 0, stream>>>(Wv, Wp, wv);
  k_score<<<dim3(8, NB), 256, 0, stream>>>(lhs, wv, score);
  k_D<<<dim3(NB, 3), 256, 0, stream>>>(lhs, mask, score, Dv);
  k_small<<<22, 256, 0, stream>>>(Dv, Wr, Wc, Lw, rels_seq, checks_seq, LD);
  k_small2<<<NB, 192, 0, stream>>>(rels_seq, checks_seq);
  k_scores<<<5000, 256, 0, stream>>>(EE, LD, scores);
  for (int hop = 0; hop < 3; hop++) {
    k_scatter<<<(NB * NT + 255) / 256, 256, 0, stream>>>(heads, rels, tails, rels_seq,
                                                         init_ent, walk, acc, hop);
    k_norm<<<NB, 1024, 0, stream>>>(acc, walk, hop);
  }
  k_final<<<NB * 3, 256, 0, stream>>>(walk, scores, checks_seq, out);
}